// Round 5
// baseline (399.919 us; speedup 1.0000x reference)
//
#include <hip/hip_runtime.h>

typedef unsigned short u16;
typedef __attribute__((ext_vector_type(8))) short short8;
typedef __attribute__((ext_vector_type(4))) float f32x4;
typedef __attribute__((ext_vector_type(4))) unsigned short us4;

__device__ __forceinline__ u16 f2bf(float f) {
    unsigned u = __float_as_uint(f);
    u += 0x7fffu + ((u >> 16) & 1u);   // round-to-nearest-even
    return (u16)(u >> 16);
}
__device__ __forceinline__ float bf2f(u16 h) {
    return __uint_as_float(((unsigned)h) << 16);
}

// ---------------- X f32 -> bf16 (4 elems/thread) ----------------
__global__ __launch_bounds__(256) void k_cvt(const float* __restrict__ in,
                                             u16* __restrict__ out, long n) {
    long i = ((long)blockIdx.x * 256 + threadIdx.x) * 4;
    if (i >= n) return;
    float4 v = *(const float4*)(in + i);
    us4 o;
    o.x = f2bf(v.x); o.y = f2bf(v.y); o.z = f2bf(v.z); o.w = f2bf(v.w);
    *(us4*)(out + i) = o;
}

// ---------------- W (K,N) f32 -> Wt (N,K) bf16, block-tri mask ----------------
__global__ __launch_bounds__(256) void k_transpose(const float* __restrict__ W,
                                                   u16* __restrict__ Wt,
                                                   int K, int N, int mask) {
    __shared__ float tile[32][33];
    const int n0 = blockIdx.x * 32, k0 = blockIdx.y * 32;
    const int tx = threadIdx.x, ty = threadIdx.y;
    if (mask && ((k0 >> 6) > (n0 >> 6))) {
        if (k0 >= ((n0 >> 8) + 1) * 256) return;   // never read by varK GEMM
#pragma unroll
        for (int j = 0; j < 32; j += 8)
            Wt[(size_t)(n0 + ty + j) * K + (k0 + tx)] = 0;
        return;
    }
#pragma unroll
    for (int j = 0; j < 32; j += 8)
        tile[ty + j][tx] = W[(size_t)(k0 + ty + j) * N + (n0 + tx)];
    __syncthreads();
#pragma unroll
    for (int j = 0; j < 32; j += 8)
        Wt[(size_t)(n0 + ty + j) * K + (k0 + tx)] = f2bf(tile[tx][ty + j]);
}

// ---------------- extract W3[:, N-1] ----------------
__global__ __launch_bounds__(256) void k_extract(const float* __restrict__ W3,
                                                 float* __restrict__ col, int N) {
    int k = blockIdx.x * 256 + threadIdx.x;
    col[k] = W3[(size_t)k * N + (N - 1)];
}

// ---------------- bf16 GEMM: C = relu(A @ Bt^T + bias) -> bf16 ----------------
// 256x256 tile, BK=64, 512 threads (8 waves 2x4), 2 LDS buffers (128 KiB),
// 4 phases/K-tile.  Tail-aware counted vmcnt ONLY at p2/p3 phase ends
// (steady-state vmcnt(4): every staged chunk gets 3-4 phases to land);
// p0/p1 ends are bare barriers.  XOR-swizzle slot^=row&7 both sides.
// LPT order for varK; XCD swizzle else.
#define BM 256
#define BN 256
#define BK 64
#define GLDS(src, dst)                                                          \
    __builtin_amdgcn_global_load_lds(                                           \
        (const __attribute__((address_space(1))) void*)(src),                   \
        (__attribute__((address_space(3))) void*)(dst), 16, 0, 0)

__global__ __launch_bounds__(512, 2) void k_gemm(const u16* __restrict__ A,
                                                 const u16* __restrict__ Bt,
                                                 const float* __restrict__ bias,
                                                 u16* __restrict__ C,
                                                 int M, int N, int K, int varK) {
    __shared__ __align__(16) u16 lds[2 * 32768];   // 128 KiB: buf{0,1} x (A 16K | B 16K elems)

    const int d = blockIdx.y * gridDim.x + blockIdx.x;
    int bx, by;
    if (varK) {   // LPT: heavy column-tiles (large keff) first
        bx = (int)gridDim.x - 1 - (d / (int)gridDim.y);
        by = d % (int)gridDim.y;
    } else {      // bijective XCD swizzle (nwg divisible by 8)
        const int nwg = (int)(gridDim.x * gridDim.y);
        const int cpx = nwg >> 3;
        const int swz = (d & 7) * cpx + (d >> 3);
        bx = swz % (int)gridDim.x;
        by = swz / (int)gridDim.x;
    }

    const int tid = (int)threadIdx.x;
    const int lane = tid & 63, wv = tid >> 6;
    const int wm = wv >> 2, wn = wv & 3;          // wave tile: 128(m) x 64(n)
    const int keff = varK ? min(K, (bx + 1) * BN) : K;
    const int nt = keff >> 6;                     // K-tiles of 64; nt >= 4 always

    const u16* Ab = A + (size_t)by * BM * K;
    const u16* Bb = Bt + (size_t)bx * BN * K;

    // ---- staging: chunk = 64 rows x 64 k = 8KB = 1 gload/thread ----
    // dest linear: buf + [A0|B 16384] + ci*4096 + tid*8
    // source row = ci*64 + (tid>>3); k-slot = (tid&7) ^ (row&7)  (pre-swizzle)
    const int tr = tid >> 3, ts = tid & 7;
    const int ss = ts ^ (tr & 7);
    const u16* aSrc = Ab + (size_t)tr * K + ss * 8;
    const u16* bSrc = Bb + (size_t)tr * K + ss * 8;

#define STA(tt, ci, dbuf) GLDS(aSrc + (size_t)(tt) * BK + (size_t)(ci) * 64 * K, \
                               lds + (dbuf) + (ci) * 4096 + tid * 8)
#define STB(tt, ci, dbuf) GLDS(bSrc + (size_t)(tt) * BK + (size_t)(ci) * 64 * K, \
                               lds + (dbuf) + 16384 + (ci) * 4096 + tid * 8)

    // ---- fragment read addressing (swizzled slot = (ks*4+(lane>>4)) ^ (l15&7)) ----
    const int l15 = lane & 15;
    const int sw = (lane >> 4) ^ (l15 & 7);
    const int arow = wm * 128 + l15;
    const int brow = wn * 64 + l15;

#define RDA(dst, mfh, ks, dbuf)                                                        \
    {                                                                                  \
        _Pragma("unroll")                                                              \
        for (int i = 0; i < 4; ++i)                                                    \
            dst[i] = *(const short8*)(lds + (dbuf) + (arow + (mfh) * 64 + i * 16) * 64 \
                                      + ((sw ^ ((ks) << 2))) * 8);                     \
    }
#define RDB(dst, ks, dbuf)                                                             \
    {                                                                                  \
        _Pragma("unroll")                                                              \
        for (int nf = 0; nf < 4; ++nf)                                                 \
            dst[nf] = *(const short8*)(lds + (dbuf) + 16384 + (brow + nf * 16) * 64    \
                                       + ((sw ^ ((ks) << 2))) * 8);                    \
    }
#define MFMA16(afS, bfS, mb)                                                           \
    {                                                                                  \
        __builtin_amdgcn_s_setprio(1);                                                 \
        _Pragma("unroll")                                                              \
        for (int i = 0; i < 4; ++i)                                                    \
            _Pragma("unroll")                                                          \
            for (int nf = 0; nf < 4; ++nf)                                             \
                acc[(mb) + i][nf] = __builtin_amdgcn_mfma_f32_16x16x32_bf16(           \
                    afS[i], bfS[nf], acc[(mb) + i][nf], 0, 0, 0);                      \
        __builtin_amdgcn_s_setprio(0);                                                 \
    }
#define MIDSYNC                                                   \
    __builtin_amdgcn_s_barrier();                                 \
    asm volatile("s_waitcnt lgkmcnt(0)" ::: "memory");            \
    __builtin_amdgcn_sched_barrier(0);
#define BARRIER __builtin_amdgcn_s_barrier()
#define VMW4 asm volatile("s_waitcnt vmcnt(4)" ::: "memory")
#define VMW2 asm volatile("s_waitcnt vmcnt(2)" ::: "memory")
#define VMW0 asm volatile("s_waitcnt vmcnt(0)" ::: "memory")

    f32x4 acc[8][4];
#pragma unroll
    for (int i = 0; i < 8; ++i)
#pragma unroll
        for (int j = 0; j < 4; ++j)
            acc[i][j] = (f32x4){0.f, 0.f, 0.f, 0.f};

    short8 afX[4], afY[4], bfA[4], bfB[4];

    // ---- prologue: stage t0 (8 chunks) + t1.b (4); t0 landed via vmcnt(4) ----
    STA(0, 0, 0); STA(0, 2, 0); STA(0, 1, 0); STA(0, 3, 0);
    STB(0, 0, 0); STB(0, 1, 0); STB(0, 2, 0); STB(0, 3, 0);
    STB(1, 0, 32768); STB(1, 1, 32768); STB(1, 2, 32768); STB(1, 3, 32768);
    VMW4;
    BARRIER;
    RDA(afX, 0, 0, 0);
    RDB(bfA, 0, 0);

    // Wait ledger (steady state), stages per phase: p0:{a0,a2}(T+1) p1:{a1,a3}(T+1)
    // p2:{b0,b1}(T+2) p3:{b2,b3}(T+2).
    //   ENDSYNC(p2): p3 reads A-low(ks0)+B(ks0) of buf(T+1) -> force a0,a2(T+1)
    //                and b0..b3(T+1); allowed outstanding = {b0,b1(T+2),a1,a3(T+1)} = 4.
    //   ENDSYNC(p3): p0 of T+1 reads A-high(ks0) -> force a1,a3(T+1);
    //                allowed = b0..b3(T+2) = 4.
    //   ENDSYNC(p0/p1): nothing newly needed -> bare barrier.
    // Tail: allowed counts shrink with skipped stages (vmcnt(2)/vmcnt(0)).
    for (int T = 0; T < nt; ++T) {
        const int bT = (T & 1) << 15;       // elem offset of buf(T)
        const int bNx = bT ^ 32768;         // buf(T+1)
        // ---- p0: compute (ks0, mf0-3); read A(mf4-7,ks0); stage T+1.a0,a2 ----
        RDA(afY, 1, 0, bT);
        if (T + 1 < nt) { STA(T + 1, 0, bNx); STA(T + 1, 2, bNx); }
        MIDSYNC;
        MFMA16(afX, bfA, 0);
        BARRIER;
        // ---- p1: compute (ks0, mf4-7); read A(mf0-3,ks1)+B(ks1); stage T+1.a1,a3 ----
        RDA(afX, 0, 1, bT);
        RDB(bfB, 1, bT);
        if (T + 1 < nt) { STA(T + 1, 1, bNx); STA(T + 1, 3, bNx); }
        MIDSYNC;
        MFMA16(afY, bfA, 4);
        BARRIER;
        // ---- p2: compute (ks1, mf0-3); read A(mf4-7,ks1); stage T+2.b0,b1 ----
        RDA(afY, 1, 1, bT);
        if (T + 2 < nt) { STB(T + 2, 0, bT); STB(T + 2, 1, bT); }
        MIDSYNC;
        MFMA16(afX, bfB, 0);
        if (T + 2 < nt) { VMW4; } else if (T + 1 < nt) { VMW2; } else { VMW0; }
        BARRIER;
        // ---- p3: compute (ks1, mf4-7); read T+1 A(mf0-3,ks0)+B(ks0); stage T+2.b2,b3 ----
        if (T + 1 < nt) {
            RDA(afX, 0, 0, bNx);
            RDB(bfA, 0, bNx);
        }
        if (T + 2 < nt) { STB(T + 2, 2, bT); STB(T + 2, 3, bT); }
        MIDSYNC;
        MFMA16(afY, bfB, 4);
        if (T + 2 < nt) { VMW4; } else { VMW0; }
        BARRIER;
    }

    // ---- epilogue: bias + relu + bf16 store ----
    const int rbase = by * BM + wm * 128 + (lane >> 4) * 4;
    const int cbase = bx * BN + wn * 64 + l15;
#pragma unroll
    for (int nf = 0; nf < 4; ++nf) {
        const int gc = cbase + nf * 16;
        const float bv = bias[gc];
#pragma unroll
        for (int mf = 0; mf < 8; ++mf) {
#pragma unroll
            for (int r = 0; r < 4; ++r) {
                int gr = rbase + mf * 16 + r;
                float h = acc[mf][nf][r] + bv;
                h = fmaxf(h, 0.0f);
                C[(size_t)gr * N + gc] = f2bf(h);
            }
        }
    }
#undef STA
#undef STB
#undef RDA
#undef RDB
#undef MFMA16
#undef MIDSYNC
#undef BARRIER
#undef VMW4
#undef VMW2
#undef VMW0
}

// ---------------- final matvec: out[m] = act[m,:] . col + b3[K-1] ----------------
__global__ __launch_bounds__(256) void k_matvec(const u16* __restrict__ act,
                                                const float* __restrict__ col,
                                                const float* __restrict__ b3,
                                                float* __restrict__ out, int K) {
    const int m = blockIdx.x, t = (int)threadIdx.x;
    const u16* row = act + (size_t)m * K;
    float acc = 0.f;
#pragma unroll
    for (int j = 0; j < 2; ++j) {
        int base = t * 16 + j * 8;
        short8 v = *(const short8*)(row + base);
#pragma unroll
        for (int u = 0; u < 8; ++u)
            acc += bf2f((u16)v[u]) * col[base + u];
    }
#pragma unroll
    for (int off = 32; off > 0; off >>= 1)
        acc += __shfl_down(acc, off);
    __shared__ float red[4];
    if ((t & 63) == 0) red[t >> 6] = acc;
    __syncthreads();
    if (t == 0) out[m] = red[0] + red[1] + red[2] + red[3] + b3[K - 1];
}

extern "C" void kernel_launch(void* const* d_in, const int* in_sizes, int n_in,
                              void* d_out, int out_size, void* d_ws, size_t ws_size,
                              hipStream_t stream) {
    const float* X  = (const float*)d_in[0];
    const float* W0 = (const float*)d_in[1];
    const float* b0 = (const float*)d_in[2];
    const float* W1 = (const float*)d_in[3];
    const float* b1 = (const float*)d_in[4];
    const float* W2 = (const float*)d_in[5];
    const float* b2 = (const float*)d_in[6];
    const float* W3 = (const float*)d_in[7];
    const float* b3 = (const float*)d_in[8];
    float* out = (float*)d_out;

    const int M = 8192, K0 = 1024, H = 4096;

    char* ws = (char*)d_ws;
    u16* Wt    = (u16*)(ws);                               // 33.5 MB (reused)
    u16* actA  = (u16*)(ws + 33554432);                    // 67.1 MB
    u16* actB  = (u16*)(ws + 33554432 + 67108864);         // 67.1 MB
    u16* Xb    = actB;                                     // alias: dead before actB written
    float* col = (float*)(ws + 33554432 + 2 * 67108864);   // 16 KB

    // 1. X -> bf16
    k_cvt<<<dim3((M * K0) / 1024), 256, 0, stream>>>(X, Xb, (long)M * K0);
    // 2. W0^T (no mask)
    k_transpose<<<dim3(H / 32, K0 / 32), dim3(32, 8), 0, stream>>>(W0, Wt, K0, H, 0);
    // 3. h0 = relu(X @ W0 + b0)
    k_gemm<<<dim3(H / BN, M / BM), 512, 0, stream>>>(Xb, Wt, b0, actA, M, H, K0, 0);
    // 4. W1^T masked
    k_transpose<<<dim3(H / 32, H / 32), dim3(32, 8), 0, stream>>>(W1, Wt, H, H, 1);
    // 5. h1 = relu(h0 @ W1eff + b1)   (variable-K per column tile, LPT order)
    k_gemm<<<dim3(H / BN, M / BM), 512, 0, stream>>>(actA, Wt, b1, actB, M, H, H, 1);
    // 6. W2^T masked
    k_transpose<<<dim3(H / 32, H / 32), dim3(32, 8), 0, stream>>>(W2, Wt, H, H, 1);
    // 7. h2 = relu(h1 @ W2eff + b2)
    k_gemm<<<dim3(H / BN, M / BM), 512, 0, stream>>>(actB, Wt, b2, actA, M, H, H, 1);
    // 8. W3 column 4095
    k_extract<<<dim3(H / 256), 256, 0, stream>>>(W3, col, H);
    // 9. out = h2 @ w3col + b3[4095]
    k_matvec<<<dim3(M), 256, 0, stream>>>(actA, col, b3, out, H);
}

// Round 8
// 393.174 us; speedup vs baseline: 1.0172x; 1.0172x over previous
//
#include <hip/hip_runtime.h>

typedef unsigned short u16;
typedef __attribute__((ext_vector_type(8))) short short8;
typedef __attribute__((ext_vector_type(4))) float f32x4;
typedef __attribute__((ext_vector_type(4))) unsigned short us4;

__device__ __forceinline__ u16 f2bf(float f) {
    unsigned u = __float_as_uint(f);
    u += 0x7fffu + ((u >> 16) & 1u);   // round-to-nearest-even
    return (u16)(u >> 16);
}
__device__ __forceinline__ float bf2f(u16 h) {
    return __uint_as_float(((unsigned)h) << 16);
}

// ---------------- X f32 -> bf16 (4 elems/thread) ----------------
__global__ __launch_bounds__(256) void k_cvt(const float* __restrict__ in,
                                             u16* __restrict__ out, long n) {
    long i = ((long)blockIdx.x * 256 + threadIdx.x) * 4;
    if (i >= n) return;
    float4 v = *(const float4*)(in + i);
    us4 o;
    o.x = f2bf(v.x); o.y = f2bf(v.y); o.z = f2bf(v.z); o.w = f2bf(v.w);
    *(us4*)(out + i) = o;
}

// ---------------- W (K,N) f32 -> Wt (N,K) bf16, block-tri mask ----------------
__global__ __launch_bounds__(256) void k_transpose(const float* __restrict__ W,
                                                   u16* __restrict__ Wt,
                                                   int K, int N, int mask) {
    __shared__ float tile[32][33];
    const int n0 = blockIdx.x * 32, k0 = blockIdx.y * 32;
    const int tx = threadIdx.x, ty = threadIdx.y;
    if (mask && ((k0 >> 6) > (n0 >> 6))) {
        if (k0 >= ((n0 >> 8) + 1) * 256) return;   // never read by varK GEMM
#pragma unroll
        for (int j = 0; j < 32; j += 8)
            Wt[(size_t)(n0 + ty + j) * K + (k0 + tx)] = 0;
        return;
    }
#pragma unroll
    for (int j = 0; j < 32; j += 8)
        tile[ty + j][tx] = W[(size_t)(k0 + ty + j) * N + (n0 + tx)];
    __syncthreads();
#pragma unroll
    for (int j = 0; j < 32; j += 8)
        Wt[(size_t)(n0 + ty + j) * K + (k0 + tx)] = f2bf(tile[tx][ty + j]);
}

// ---------------- extract W3[:, N-1] ----------------
__global__ __launch_bounds__(256) void k_extract(const float* __restrict__ W3,
                                                 float* __restrict__ col, int N) {
    int k = blockIdx.x * 256 + threadIdx.x;
    col[k] = W3[(size_t)k * N + (N - 1)];
}

// ---------------- bf16 GEMM: C = relu(A @ Bt^T + bias) -> bf16 ----------------
// 256x256 tile, BK=32, 512 threads (8 waves 2x4), QUAD-buffered LDS (4x32 KiB),
// 2 phases/tile, stage T+3 during T (>=4-phase landing slack).  One tail-aware
// vmcnt per tile BEFORE the p0-end barrier (per-wave landing propagates via the
// barrier).  No explicit lgkm drains (compiler emits counted lgkmcnt before the
// consuming MFMA -> ds_reads drain under MFMA).  2-tile unroll with TWO named B
// register sets (bfP/bfQ): p1's next-tile B prefetch must NOT overwrite the B
// still consumed by p1's MFMA (the R6/R7 deterministic bug).  sched_barrier(0)
// pins MFMA before each phase-end barrier.  XOR-swizzle slot^=(row>>1)&3 both
// sides (64B rows -> 2-way max aliasing, free per m136).
#define BM 256
#define BN 256
#define BK 32
#define BUFE 16384                     // elems per buffer: A 8192 | B 8192
#define GLDS(src, dst)                                                          \
    __builtin_amdgcn_global_load_lds(                                           \
        (const __attribute__((address_space(1))) void*)(src),                   \
        (__attribute__((address_space(3))) void*)(dst), 16, 0, 0)

__global__ __launch_bounds__(512, 2) void k_gemm(const u16* __restrict__ A,
                                                 const u16* __restrict__ Bt,
                                                 const float* __restrict__ bias,
                                                 u16* __restrict__ C,
                                                 int M, int N, int K, int varK) {
    __shared__ __align__(16) u16 lds[4 * BUFE];   // 128 KiB

    const int d = blockIdx.y * gridDim.x + blockIdx.x;
    int bx, by;
    if (varK) {   // LPT: heavy column-tiles (large keff) first
        bx = (int)gridDim.x - 1 - (d / (int)gridDim.y);
        by = d % (int)gridDim.y;
    } else {      // bijective XCD swizzle (nwg divisible by 8)
        const int nwg = (int)(gridDim.x * gridDim.y);
        const int cpx = nwg >> 3;
        const int swz = (d & 7) * cpx + (d >> 3);
        bx = swz % (int)gridDim.x;
        by = swz / (int)gridDim.x;
    }

    const int tid = (int)threadIdx.x;
    const int lane = tid & 63, wv = tid >> 6;
    const int wm = wv >> 2, wn = wv & 3;          // wave tile: 128(m) x 64(n)
    const int keff = varK ? min(K, (bx + 1) * BN) : K;
    const int nt = keff >> 5;                     // K-tiles of 32; nt even, >= 8

    const u16* Ab = A + (size_t)by * BM * K;
    const u16* Bb = Bt + (size_t)bx * BN * K;

    // ---- staging: chunk = 128 rows x 32 k = 8KB = 1 gload/thread; 2+2/tile ----
    // dest linear: buf + [A0|B 8192] + ci*4096 + tid*8
    // source row = ci*128 + (tid>>2); k-slot = (tid&3) ^ ((row>>1)&3)  (pre-swizzle)
    const int tr = tid >> 2, ts = tid & 3;
    const int ss = ts ^ ((tr >> 1) & 3);
    const u16* aSrc = Ab + (size_t)tr * K + ss * 8;
    const u16* bSrc = Bb + (size_t)tr * K + ss * 8;

#define STA(tt, ci, dbuf) GLDS(aSrc + (size_t)(tt) * BK + (size_t)(ci) * 128 * K, \
                               lds + (dbuf) + (ci) * 4096 + tid * 8)
#define STB(tt, ci, dbuf) GLDS(bSrc + (size_t)(tt) * BK + (size_t)(ci) * 128 * K, \
                               lds + (dbuf) + 8192 + (ci) * 4096 + tid * 8)

    // ---- fragment reads (swizzled slot = (lane>>4) ^ ((row>>1)&3)) ----
    const int l15 = lane & 15;
    const int sw = (lane >> 4) ^ ((l15 >> 1) & 3);
    const int arow = wm * 128 + l15;
    const int brow = wn * 64 + l15;

#define RDA(dst, mfh, dbuf)                                                          \
    {                                                                                \
        _Pragma("unroll")                                                            \
        for (int i = 0; i < 4; ++i)                                                  \
            dst[i] = *(const short8*)(lds + (dbuf) + (arow + (mfh) * 64 + i * 16) * 32 \
                                      + sw * 8);                                     \
    }
#define RDB(dst, dbuf)                                                               \
    {                                                                                \
        _Pragma("unroll")                                                            \
        for (int nf = 0; nf < 4; ++nf)                                               \
            dst[nf] = *(const short8*)(lds + (dbuf) + 8192 + (brow + nf * 16) * 32   \
                                       + sw * 8);                                    \
    }
#define MFMA16(afS, bfS, mb)                                                         \
    {                                                                                \
        __builtin_amdgcn_s_setprio(1);                                              \
        _Pragma("unroll")                                                            \
        for (int i = 0; i < 4; ++i)                                                  \
            _Pragma("unroll")                                                        \
            for (int nf = 0; nf < 4; ++nf)                                           \
                acc[(mb) + i][nf] = __builtin_amdgcn_mfma_f32_16x16x32_bf16(         \
                    afS[i], bfS[nf], acc[(mb) + i][nf], 0, 0, 0);                    \
        __builtin_amdgcn_s_setprio(0);                                              \
    }
#define PHASE_END                                                 \
    __builtin_amdgcn_sched_barrier(0);                            \
    asm volatile("s_barrier" ::: "memory");
#define VMW6 asm volatile("s_waitcnt vmcnt(6)" ::: "memory")
#define VMW4 asm volatile("s_waitcnt vmcnt(4)" ::: "memory")
#define VMW0 asm volatile("s_waitcnt vmcnt(0)" ::: "memory")

    f32x4 acc[8][4];
#pragma unroll
    for (int i = 0; i < 8; ++i)
#pragma unroll
        for (int j = 0; j < 4; ++j)
            acc[i][j] = (f32x4){0.f, 0.f, 0.f, 0.f};

    short8 afX[4], afY[4], bfP[4], bfQ[4];

    // ---- prologue: stage tiles 0,1,2 (12 loads); force tile 0 via vmcnt(8)
    //      BEFORE the barrier (cross-wave propagation) ----
    STA(0, 0, 0);     STA(0, 1, 0);     STB(0, 0, 0);     STB(0, 1, 0);
    STA(1, 0, BUFE);  STA(1, 1, BUFE);  STB(1, 0, BUFE);  STB(1, 1, BUFE);
    STA(2, 0, 2*BUFE);STA(2, 1, 2*BUFE);STB(2, 0, 2*BUFE);STB(2, 1, 2*BUFE);
    asm volatile("s_waitcnt vmcnt(8)" ::: "memory");
    asm volatile("s_barrier" ::: "memory");
    RDA(afX, 0, 0);
    RDB(bfP, 0);

    // Ledger (per wave): tile U's chunks staged at (U-3).{p0:A, p1:B}.
    // At T.p0-end (after MFMA, before barrier): force tile T+1's A+B landed;
    // allowed outstanding newer = {T+2 A,B}(4 if T+2<nt) + {T+3 A}(2 if T+3<nt)
    //   -> vmcnt 6 / 4 / 0; skipped only when T+1>=nt (last tile's p1 reads none).
    // WAR: STA(T+3) writes buf (T-1)&3; buf(T-1)'s last ds_reads were drained
    // (compiler lgkm wait) before the MFMAs pinned before earlier barriers.
    for (int T = 0; T < nt; T += 2) {
        const int U = T + 1;                 // U < nt always (nt even)
        const int bT = (T & 3) * BUFE;
        const int bU = ((T + 1) & 3) * BUFE;
        const int bV = ((T + 2) & 3) * BUFE;
        const int bZ1 = ((T + 3) & 3) * BUFE;
        const int bZ2 = ((T + 4) & 3) * BUFE;
        // ---- T.p0: read A-high(T); stage T+3.a; MFMA m0-3 (B=bfP); vmcnt; bar ----
        RDA(afY, 1, bT);
        if (T + 3 < nt) { STA(T + 3, 0, bZ1); STA(T + 3, 1, bZ1); }
        MFMA16(afX, bfP, 0);
        if (T + 3 < nt) { VMW6; } else { VMW0; }   // T+2<nt is impossible w/o T+3<nt here? (T even, nt even): T+2==nt when T=nt-2 -> VMW0 correct
        PHASE_END;
        // ---- T.p1: read T+1 A-low + B->bfQ; stage T+3.b; MFMA m4-7 (B=bfP); bar ----
        RDA(afX, 0, bU);
        RDB(bfQ, bU);
        if (T + 3 < nt) { STB(T + 3, 0, bZ1); STB(T + 3, 1, bZ1); }
        MFMA16(afY, bfP, 4);
        PHASE_END;
        // ---- U.p0: read A-high(U); stage U+3.a; MFMA m0-3 (B=bfQ); vmcnt; bar ----
        RDA(afY, 1, bU);
        if (U + 3 < nt) { STA(U + 3, 0, bZ2); STA(U + 3, 1, bZ2); }
        MFMA16(afX, bfQ, 0);
        if (U + 1 < nt) {
            if (U + 3 < nt) { VMW6; } else if (U + 2 < nt) { VMW4; } else { VMW0; }
        }
        PHASE_END;
        // ---- U.p1: read U+1 A-low + B->bfP (if any); stage U+3.b; MFMA m4-7 (B=bfQ); bar ----
        if (U + 1 < nt) {
            RDA(afX, 0, bV);
            RDB(bfP, bV);
        }
        if (U + 3 < nt) { STB(U + 3, 0, bZ2); STB(U + 3, 1, bZ2); }
        MFMA16(afY, bfQ, 4);
        PHASE_END;
    }

    // ---- epilogue: bias + relu + bf16 store ----
    const int rbase = by * BM + wm * 128 + (lane >> 4) * 4;
    const int cbase = bx * BN + wn * 64 + l15;
#pragma unroll
    for (int nf = 0; nf < 4; ++nf) {
        const int gc = cbase + nf * 16;
        const float bv = bias[gc];
#pragma unroll
        for (int mf = 0; mf < 8; ++mf) {
#pragma unroll
            for (int r = 0; r < 4; ++r) {
                int gr = rbase + mf * 16 + r;
                float h = acc[mf][nf][r] + bv;
                h = fmaxf(h, 0.0f);
                C[(size_t)gr * N + gc] = f2bf(h);
            }
        }
    }
#undef STA
#undef STB
#undef RDA
#undef RDB
#undef MFMA16
#undef PHASE_END
#undef VMW6
#undef VMW4
#undef VMW0
}

// ---------------- final matvec: out[m] = act[m,:] . col + b3[K-1] ----------------
__global__ __launch_bounds__(256) void k_matvec(const u16* __restrict__ act,
                                                const float* __restrict__ col,
                                                const float* __restrict__ b3,
                                                float* __restrict__ out, int K) {
    const int m = blockIdx.x, t = (int)threadIdx.x;
    const u16* row = act + (size_t)m * K;
    float acc = 0.f;
#pragma unroll
    for (int j = 0; j < 2; ++j) {
        int base = t * 16 + j * 8;
        short8 v = *(const short8*)(row + base);
#pragma unroll
        for (int u = 0; u < 8; ++u)
            acc += bf2f((u16)v[u]) * col[base + u];
    }
#pragma unroll
    for (int off = 32; off > 0; off >>= 1)
        acc += __shfl_down(acc, off);
    __shared__ float red[4];
    if ((t & 63) == 0) red[t >> 6] = acc;
    __syncthreads();
    if (t == 0) out[m] = red[0] + red[1] + red[2] + red[3] + b3[K - 1];
}

extern "C" void kernel_launch(void* const* d_in, const int* in_sizes, int n_in,
                              void* d_out, int out_size, void* d_ws, size_t ws_size,
                              hipStream_t stream) {
    const float* X  = (const float*)d_in[0];
    const float* W0 = (const float*)d_in[1];
    const float* b0 = (const float*)d_in[2];
    const float* W1 = (const float*)d_in[3];
    const float* b1 = (const float*)d_in[4];
    const float* W2 = (const float*)d_in[5];
    const float* b2 = (const float*)d_in[6];
    const float* W3 = (const float*)d_in[7];
    const float* b3 = (const float*)d_in[8];
    float* out = (float*)d_out;

    const int M = 8192, K0 = 1024, H = 4096;

    char* ws = (char*)d_ws;
    u16* Wt    = (u16*)(ws);                               // 33.5 MB (reused)
    u16* actA  = (u16*)(ws + 33554432);                    // 67.1 MB
    u16* actB  = (u16*)(ws + 33554432 + 67108864);         // 67.1 MB
    u16* Xb    = actB;                                     // alias: dead before actB written
    float* col = (float*)(ws + 33554432 + 2 * 67108864);   // 16 KB

    // 1. X -> bf16
    k_cvt<<<dim3((M * K0) / 1024), 256, 0, stream>>>(X, Xb, (long)M * K0);
    // 2. W0^T (no mask)
    k_transpose<<<dim3(H / 32, K0 / 32), dim3(32, 8), 0, stream>>>(W0, Wt, K0, H, 0);
    // 3. h0 = relu(X @ W0 + b0)
    k_gemm<<<dim3(H / BN, M / BM), 512, 0, stream>>>(Xb, Wt, b0, actA, M, H, K0, 0);
    // 4. W1^T masked
    k_transpose<<<dim3(H / 32, H / 32), dim3(32, 8), 0, stream>>>(W1, Wt, H, H, 1);
    // 5. h1 = relu(h0 @ W1eff + b1)   (variable-K per column tile, LPT order)
    k_gemm<<<dim3(H / BN, M / BM), 512, 0, stream>>>(actA, Wt, b1, actB, M, H, H, 1);
    // 6. W2^T masked
    k_transpose<<<dim3(H / 32, H / 32), dim3(32, 8), 0, stream>>>(W2, Wt, H, H, 1);
    // 7. h2 = relu(h1 @ W2eff + b2)
    k_gemm<<<dim3(H / BN, M / BM), 512, 0, stream>>>(actB, Wt, b2, actA, M, H, H, 1);
    // 8. W3 column 4095
    k_extract<<<dim3(H / 256), 256, 0, stream>>>(W3, col, H);
    // 9. out = h2 @ w3col + b3[4095]
    k_matvec<<<dim3(M), 256, 0, stream>>>(actA, col, b3, out, H);
}